// Round 2
// baseline (13479.311 us; speedup 1.0000x reference)
//
#include <hip/hip_runtime.h>

// APPNP-style propagation: 4 hops of M = 0.9*A_hat + 0.1*I applied to x[N,128], y[N,32].
// NOTE: reference mixes ALPHA with the CURRENT iterate, so the self-loop + mix fold into
// one per-node scale: next[i] = (0.9*dinv[i]^2 + 0.1)*cur[i], then edge scatter adds.
// Round 2: fix alpha-mix (use cur not orig); robust int32/int64 edge_index handling.

#define NN 100000
#define EE 1600000
#define DXX 128
#define DYY 32

// Detect whether raw edge_index buffer is int64 (high words all zero) or int32.
__global__ void detect_kernel(const int* __restrict__ raw, int* __restrict__ flag) {
    if (threadIdx.x == 0 && blockIdx.x == 0) {
        int is64 = 1;
        for (int k = 1; k < 16; k += 2) {
            if (raw[k] != 0) { is64 = 0; break; }
        }
        *flag = is64;
    }
}

// Normalize edge_index into a flat int32 array idx[2E].
__global__ void convert_kernel(const void* __restrict__ raw, const int* __restrict__ flag,
                               int* __restrict__ idx) {
    int e = blockIdx.x * blockDim.x + threadIdx.x;
    if (e < 2 * EE) {
        if (*flag) {
            idx[e] = (int)((const long long*)raw)[e];
        } else {
            idx[e] = ((const int*)raw)[e];
        }
    }
}

// deg[i] = 1 (self loop) + count of dst==i
__global__ void deg_init_kernel(float* __restrict__ deg) {
    int i = blockIdx.x * blockDim.x + threadIdx.x;
    if (i < NN) deg[i] = 1.0f;
}

__global__ void deg_count_kernel(const int* __restrict__ idx, float* __restrict__ deg) {
    int e = blockIdx.x * blockDim.x + threadIdx.x;
    if (e < EE) {
        atomicAdd(&deg[idx[EE + e]], 1.0f);
    }
}

__global__ void dinv_kernel(float* __restrict__ deg) {
    int i = blockIdx.x * blockDim.x + threadIdx.x;
    if (i < NN) deg[i] = rsqrtf(deg[i]);
}

// w[e] = 0.9 * dinv[src] * dinv[dst]
__global__ void w_kernel(const int* __restrict__ idx, const float* __restrict__ dinv,
                         float* __restrict__ w) {
    int e = blockIdx.x * blockDim.x + threadIdx.x;
    if (e < EE) {
        int s = idx[e], d = idx[EE + e];
        w[e] = 0.9f * dinv[s] * dinv[d];
    }
}

// next[i,:] = (0.9*dinv[i]^2 + 0.1) * cur[i,:]   (self-loop + alpha-mix of CURRENT iterate)
__global__ void init_kernel(const float4* __restrict__ cur, const float* __restrict__ dinv,
                            float4* __restrict__ next, int total4, int log2dim4) {
    int i = blockIdx.x * blockDim.x + threadIdx.x;
    if (i < total4) {
        int node = i >> log2dim4;
        float di = dinv[node];
        float s = 0.9f * di * di + 0.1f;
        float4 c = cur[i];
        float4 r;
        r.x = s * c.x;
        r.y = s * c.y;
        r.z = s * c.z;
        r.w = s * c.w;
        next[i] = r;
    }
}

// 32 lanes per edge, float4 each -> 128 floats. out[src] += w * v[dst]
__global__ void edge_x_kernel(const int* __restrict__ idx, const float* __restrict__ w,
                              const float4* __restrict__ cur, float* __restrict__ next) {
    int t = blockIdx.x * blockDim.x + threadIdx.x;
    int e = t >> 5;
    int lane = t & 31;
    if (e < EE) {
        int s = idx[e], d = idx[EE + e];
        float we = w[e];
        float4 v = cur[(size_t)d * 32 + lane];
        float* p = next + (size_t)s * DXX + lane * 4;
        atomicAdd(p + 0, we * v.x);
        atomicAdd(p + 1, we * v.y);
        atomicAdd(p + 2, we * v.z);
        atomicAdd(p + 3, we * v.w);
    }
}

// 8 lanes per edge, float4 each -> 32 floats
__global__ void edge_y_kernel(const int* __restrict__ idx, const float* __restrict__ w,
                              const float4* __restrict__ cur, float* __restrict__ next) {
    int t = blockIdx.x * blockDim.x + threadIdx.x;
    int e = t >> 3;
    int lane = t & 7;
    if (e < EE) {
        int s = idx[e], d = idx[EE + e];
        float we = w[e];
        float4 v = cur[(size_t)d * 8 + lane];
        float* p = next + (size_t)s * DYY + lane * 4;
        atomicAdd(p + 0, we * v.x);
        atomicAdd(p + 1, we * v.y);
        atomicAdd(p + 2, we * v.z);
        atomicAdd(p + 3, we * v.w);
    }
}

extern "C" void kernel_launch(void* const* d_in, const int* in_sizes, int n_in,
                              void* d_out, int out_size, void* d_ws, size_t ws_size,
                              hipStream_t stream) {
    const float* x0  = (const float*)d_in[0];
    const float* y0  = (const float*)d_in[1];
    const void*  raw = d_in[2];   // [2,E] flattened, int32 or int64 (detected on device)

    float* out_x = (float*)d_out;
    float* out_y = out_x + (size_t)NN * DXX;

    // ws layout (4-byte units): flag[16] | idx[2E] | dinv[100096] | w[E] | xA[N*DX] | yA[N*DY]
    // total ~= 96.5 MB
    int*   flag = (int*)d_ws;
    int*   idx  = flag + 16;
    float* dinv = (float*)(idx + 2 * EE);
    float* w    = dinv + 100096;
    float* xA   = w + EE;
    float* yA   = xA + (size_t)NN * DXX;

    const int B = 256;

    detect_kernel<<<1, 64, 0, stream>>>((const int*)raw, flag);
    convert_kernel<<<(2 * EE + B - 1) / B, B, 0, stream>>>(raw, flag, idx);

    deg_init_kernel<<<(NN + B - 1) / B, B, 0, stream>>>(dinv);
    deg_count_kernel<<<(EE + B - 1) / B, B, 0, stream>>>(idx, dinv);
    dinv_kernel<<<(NN + B - 1) / B, B, 0, stream>>>(dinv);
    w_kernel<<<(EE + B - 1) / B, B, 0, stream>>>(idx, dinv, w);

    const float* xc = x0;
    const float* yc = y0;
    for (int h = 0; h < 4; ++h) {
        // ping-pong: h=0 -> ws, h=1 -> d_out, h=2 -> ws, h=3 -> d_out (final lands in d_out)
        float* xn = (h & 1) ? out_x : xA;
        float* yn = (h & 1) ? out_y : yA;

        init_kernel<<<(NN * (DXX / 4) + B - 1) / B, B, 0, stream>>>(
            (const float4*)xc, dinv, (float4*)xn, NN * (DXX / 4), 5);
        init_kernel<<<(NN * (DYY / 4) + B - 1) / B, B, 0, stream>>>(
            (const float4*)yc, dinv, (float4*)yn, NN * (DYY / 4), 3);

        edge_x_kernel<<<(EE * 32 + B - 1) / B, B, 0, stream>>>(idx, w, (const float4*)xc, xn);
        edge_y_kernel<<<(EE * 8 + B - 1) / B, B, 0, stream>>>(idx, w, (const float4*)yc, yn);

        xc = xn;
        yc = yn;
    }
}

// Round 3
// 1066.454 us; speedup vs baseline: 12.6394x; 12.6394x over previous
//
#include <hip/hip_runtime.h>

// APPNP-style propagation: 4 hops of M = 0.9*A_hat + 0.1*I on x[N,128], y[N,32].
// Round 3: scatter-atomics -> CSR gather. Build CSR (by src) on device each launch:
//   outdeg count -> 2-level exclusive scan -> atomic-cursor scatter of dst.
// Gather factors dinv[src] out of the row sum, so only dst_sorted[E] is stored.
// Self-loop + alpha-mix fused into gather epilogue (no init kernel, no atomics in hops).

#define NN 100000
#define EE 1600000
#define DXX 128
#define DYY 32
#define SCAN_B 1024
#define NB 98   // ceil(NN / SCAN_B)

// ---------- preprocessing ----------

// Detect whether raw edge_index buffer is int64 (high words all zero) or int32.
__global__ void detect_kernel(const int* __restrict__ raw, int* __restrict__ flag) {
    if (threadIdx.x == 0 && blockIdx.x == 0) {
        int is64 = 1;
        for (int k = 1; k < 16; k += 2) {
            if (raw[k] != 0) { is64 = 0; break; }
        }
        *flag = is64;
    }
}

__global__ void convert_kernel(const void* __restrict__ raw, const int* __restrict__ flag,
                               int* __restrict__ idx) {
    int e = blockIdx.x * blockDim.x + threadIdx.x;
    if (e < 2 * EE) {
        if (*flag) idx[e] = (int)((const long long*)raw)[e];
        else       idx[e] = ((const int*)raw)[e];
    }
}

// degf[i] = 1.0 (self loop), outdeg[i] = 0
__global__ void zero_kernel(float* __restrict__ degf, int* __restrict__ outdeg) {
    int i = blockIdx.x * blockDim.x + threadIdx.x;
    if (i < NN) { degf[i] = 1.0f; outdeg[i] = 0; }
}

__global__ void count_kernel(const int* __restrict__ idx, float* __restrict__ degf,
                             int* __restrict__ outdeg) {
    int e = blockIdx.x * blockDim.x + threadIdx.x;
    if (e < EE) {
        atomicAdd(&degf[idx[EE + e]], 1.0f);   // in-degree on dst (normalization)
        atomicAdd(&outdeg[idx[e]], 1);         // out-degree on src (CSR rows)
    }
}

__global__ void dinv_kernel(float* __restrict__ deg) {
    int i = blockIdx.x * blockDim.x + threadIdx.x;
    if (i < NN) deg[i] = rsqrtf(deg[i]);
}

// Block-local exclusive scan of outdeg -> rowptr; block totals -> blocksums.
__global__ void scan1_kernel(const int* __restrict__ outdeg, int* __restrict__ rowptr,
                             int* __restrict__ blocksums) {
    __shared__ int s[SCAN_B];
    int tid = threadIdx.x;
    int gid = blockIdx.x * SCAN_B + tid;
    int od = (gid < NN) ? outdeg[gid] : 0;
    s[tid] = od;
    __syncthreads();
    for (int off = 1; off < SCAN_B; off <<= 1) {
        int t = (tid >= off) ? s[tid - off] : 0;
        __syncthreads();
        s[tid] += t;
        __syncthreads();
    }
    if (gid < NN) rowptr[gid] = s[tid] - od;    // local exclusive
    if (tid == SCAN_B - 1) blocksums[blockIdx.x] = s[tid];
}

// Exclusive scan of the 98 block sums (single block of 128).
__global__ void scan2_kernel(int* __restrict__ blocksums, int* __restrict__ rowptr) {
    __shared__ int s[128];
    int tid = threadIdx.x;
    int v = (tid < NB) ? blocksums[tid] : 0;
    s[tid] = v;
    __syncthreads();
    for (int off = 1; off < 128; off <<= 1) {
        int t = (tid >= off) ? s[tid - off] : 0;
        __syncthreads();
        s[tid] += t;
        __syncthreads();
    }
    if (tid < NB) blocksums[tid] = s[tid] - v;  // exclusive, in place
    if (tid == 0) rowptr[NN] = EE;
}

// Add block offsets; copy rowptr into cursor for the scatter.
__global__ void scan3_kernel(int* __restrict__ rowptr, const int* __restrict__ blocksums,
                             int* __restrict__ cursor) {
    int i = blockIdx.x * blockDim.x + threadIdx.x;
    if (i < NN) {
        int r = rowptr[i] + blocksums[i >> 10];
        rowptr[i] = r;
        cursor[i] = r;
    }
}

// Bucket edges by src: dst_sorted[pos] = dst.
__global__ void scatter_kernel(const int* __restrict__ idx, int* __restrict__ cursor,
                               int* __restrict__ dst_sorted) {
    int e = blockIdx.x * blockDim.x + threadIdx.x;
    if (e < EE) {
        int s = idx[e], d = idx[EE + e];
        int pos = atomicAdd(&cursor[s], 1);
        dst_sorted[pos] = d;
    }
}

// ---------- per-hop gather ----------

// 32 lanes per row, float4 each -> 128 floats.
// out[i] = 0.9*dinv[i]*sum_e dinv[dst_e]*cur[dst_e] + (0.9*dinv[i]^2 + 0.1)*cur[i]
__global__ void gather_x_kernel(const int* __restrict__ rowptr, const int* __restrict__ dst_sorted,
                                const float* __restrict__ dinv, const float4* __restrict__ cur,
                                float4* __restrict__ next) {
    int t = blockIdx.x * blockDim.x + threadIdx.x;
    int row = t >> 5;
    int lane = t & 31;
    if (row >= NN) return;
    int beg = rowptr[row], end = rowptr[row + 1];
    float4 acc = make_float4(0.f, 0.f, 0.f, 0.f);
    for (int e = beg; e < end; ++e) {
        int d = dst_sorted[e];
        float dv = dinv[d];
        float4 v = cur[(size_t)d * 32 + lane];
        acc.x += dv * v.x;
        acc.y += dv * v.y;
        acc.z += dv * v.z;
        acc.w += dv * v.w;
    }
    float di = dinv[row];
    float sg = 0.9f * di;                 // hoisted dinv[src] * 0.9
    float sl = 0.9f * di * di + 0.1f;     // self loop + alpha mix
    float4 c = cur[(size_t)row * 32 + lane];
    float4 r;
    r.x = sg * acc.x + sl * c.x;
    r.y = sg * acc.y + sl * c.y;
    r.z = sg * acc.z + sl * c.z;
    r.w = sg * acc.w + sl * c.w;
    next[(size_t)row * 32 + lane] = r;
}

// 8 lanes per row, float4 each -> 32 floats.
__global__ void gather_y_kernel(const int* __restrict__ rowptr, const int* __restrict__ dst_sorted,
                                const float* __restrict__ dinv, const float4* __restrict__ cur,
                                float4* __restrict__ next) {
    int t = blockIdx.x * blockDim.x + threadIdx.x;
    int row = t >> 3;
    int lane = t & 7;
    if (row >= NN) return;
    int beg = rowptr[row], end = rowptr[row + 1];
    float4 acc = make_float4(0.f, 0.f, 0.f, 0.f);
    for (int e = beg; e < end; ++e) {
        int d = dst_sorted[e];
        float dv = dinv[d];
        float4 v = cur[(size_t)d * 8 + lane];
        acc.x += dv * v.x;
        acc.y += dv * v.y;
        acc.z += dv * v.z;
        acc.w += dv * v.w;
    }
    float di = dinv[row];
    float sg = 0.9f * di;
    float sl = 0.9f * di * di + 0.1f;
    float4 c = cur[(size_t)row * 8 + lane];
    float4 r;
    r.x = sg * acc.x + sl * c.x;
    r.y = sg * acc.y + sl * c.y;
    r.z = sg * acc.z + sl * c.z;
    r.w = sg * acc.w + sl * c.w;
    next[(size_t)row * 8 + lane] = r;
}

extern "C" void kernel_launch(void* const* d_in, const int* in_sizes, int n_in,
                              void* d_out, int out_size, void* d_ws, size_t ws_size,
                              hipStream_t stream) {
    const float* x0  = (const float*)d_in[0];
    const float* y0  = (const float*)d_in[1];
    const void*  raw = d_in[2];   // [2,E] flattened, int32 or int64 (detected on device)

    float* out_x = (float*)d_out;
    float* out_y = out_x + (size_t)NN * DXX;

    // ws layout (4-byte units):
    // flag[16] | idx[2E] | dinv[100096] | outdeg[100096] | rowptr[100112] | cursor[100096]
    // | blocksums[128] | dst_sorted[E] | xA[N*DX] | yA[N*DY]   ~= 85 MB
    int*   flag      = (int*)d_ws;
    int*   idx       = flag + 16;
    float* dinv      = (float*)(idx + 2 * EE);
    int*   outdeg    = (int*)(dinv + 100096);
    int*   rowptr    = outdeg + 100096;
    int*   cursor    = rowptr + 100112;
    int*   blocksums = cursor + 100096;
    int*   dst_sorted= blocksums + 128;
    float* xA        = (float*)(dst_sorted + EE);
    float* yA        = xA + (size_t)NN * DXX;

    const int B = 256;

    detect_kernel<<<1, 64, 0, stream>>>((const int*)raw, flag);
    convert_kernel<<<(2 * EE + B - 1) / B, B, 0, stream>>>(raw, flag, idx);
    zero_kernel<<<(NN + B - 1) / B, B, 0, stream>>>(dinv, outdeg);
    count_kernel<<<(EE + B - 1) / B, B, 0, stream>>>(idx, dinv, outdeg);
    dinv_kernel<<<(NN + B - 1) / B, B, 0, stream>>>(dinv);
    scan1_kernel<<<NB, SCAN_B, 0, stream>>>(outdeg, rowptr, blocksums);
    scan2_kernel<<<1, 128, 0, stream>>>(blocksums, rowptr);
    scan3_kernel<<<(NN + B - 1) / B, B, 0, stream>>>(rowptr, blocksums, cursor);
    scatter_kernel<<<(EE + B - 1) / B, B, 0, stream>>>(idx, cursor, dst_sorted);

    const float* xc = x0;
    const float* yc = y0;
    for (int h = 0; h < 4; ++h) {
        // ping-pong: h=0 -> ws, h=1 -> d_out, h=2 -> ws, h=3 -> d_out (final lands in d_out)
        float* xn = (h & 1) ? out_x : xA;
        float* yn = (h & 1) ? out_y : yA;

        gather_x_kernel<<<(NN * 32 + B - 1) / B, B, 0, stream>>>(
            rowptr, dst_sorted, dinv, (const float4*)xc, (float4*)xn);
        gather_y_kernel<<<(NN * 8 + B - 1) / B, B, 0, stream>>>(
            rowptr, dst_sorted, dinv, (const float4*)yc, (float4*)yn);

        xc = xn;
        yc = yn;
    }
}

// Round 4
// 1039.470 us; speedup vs baseline: 12.9675x; 1.0260x over previous
//
#include <hip/hip_runtime.h>

// APPNP-style propagation: 4 hops of M = 0.9*A_hat + 0.1*I on x[N,128], y[N,32].
// Round 4: (a) K=8 replicated counters/cursors to cut atomic line contention 8x,
// (b) gather_x = one 64-lane wave per row, 2 edges in flight + cross-half shuffle reduce,
// (c) gather_y = 8 edge-groups x 8 lanes + 3-step shuffle reduce.

#define NN 100000
#define EE 1600000
#define DXX 128
#define DYY 32
#define NPAD 100096     // N padded to multiple of 64
#define KREP 8
#define SCAN_B 1024
#define NB 98           // ceil(NN / SCAN_B)

// ---------- preprocessing ----------

__global__ void detect_kernel(const int* __restrict__ raw, int* __restrict__ flag) {
    if (threadIdx.x == 0 && blockIdx.x == 0) {
        int is64 = 1;
        for (int k = 1; k < 16; k += 2) {
            if (raw[k] != 0) { is64 = 0; break; }
        }
        *flag = is64;
    }
}

__global__ void convert_kernel(const void* __restrict__ raw, const int* __restrict__ flag,
                               int* __restrict__ idx) {
    int e = blockIdx.x * blockDim.x + threadIdx.x;
    if (e < 2 * EE) {
        if (*flag) idx[e] = (int)((const long long*)raw)[e];
        else       idx[e] = ((const int*)raw)[e];
    }
}

// zero indeg_rep + outdeg_rep (2*KREP*NPAD ints, contiguous)
__global__ void zero_kernel(int* __restrict__ bufs) {
    int i = blockIdx.x * blockDim.x + threadIdx.x;
    if (i < 2 * KREP * NPAD) bufs[i] = 0;
}

// replica r = e & 7: in-degree on dst, out-degree on src
__global__ void count_kernel(const int* __restrict__ idx, int* __restrict__ indeg_rep,
                             int* __restrict__ outdeg_rep) {
    int e = blockIdx.x * blockDim.x + threadIdx.x;
    if (e < EE) {
        int r = e & (KREP - 1);
        int s = idx[e], d = idx[EE + e];
        atomicAdd(&outdeg_rep[r * NPAD + s], 1);
        atomicAdd(&indeg_rep[r * NPAD + d], 1);
    }
}

// Block-local exclusive scan of total outdeg -> rowptr(local); block totals -> blocksums.
__global__ void scan1_kernel(const int* __restrict__ outdeg_rep, int* __restrict__ rowptr,
                             int* __restrict__ blocksums) {
    __shared__ int s[SCAN_B];
    int tid = threadIdx.x;
    int gid = blockIdx.x * SCAN_B + tid;
    int od = 0;
    if (gid < NN) {
        #pragma unroll
        for (int r = 0; r < KREP; ++r) od += outdeg_rep[r * NPAD + gid];
    }
    s[tid] = od;
    __syncthreads();
    for (int off = 1; off < SCAN_B; off <<= 1) {
        int t = (tid >= off) ? s[tid - off] : 0;
        __syncthreads();
        s[tid] += t;
        __syncthreads();
    }
    if (gid < NN) rowptr[gid] = s[tid] - od;
    if (tid == SCAN_B - 1) blocksums[blockIdx.x] = s[tid];
}

__global__ void scan2_kernel(int* __restrict__ blocksums, int* __restrict__ rowptr) {
    __shared__ int s[128];
    int tid = threadIdx.x;
    int v = (tid < NB) ? blocksums[tid] : 0;
    s[tid] = v;
    __syncthreads();
    for (int off = 1; off < 128; off <<= 1) {
        int t = (tid >= off) ? s[tid - off] : 0;
        __syncthreads();
        s[tid] += t;
        __syncthreads();
    }
    if (tid < NB) blocksums[tid] = s[tid] - v;
    if (tid == 0) rowptr[NN] = EE;
}

// Finalize rowptr; init per-replica cursors (exclusive prefix over replicas); compute dinv.
__global__ void scan3_kernel(int* __restrict__ rowptr, const int* __restrict__ blocksums,
                             const int* __restrict__ indeg_rep, const int* __restrict__ outdeg_rep,
                             int* __restrict__ cursor_rep, float* __restrict__ dinv) {
    int i = blockIdx.x * blockDim.x + threadIdx.x;
    if (i < NN) {
        int base = rowptr[i] + blocksums[i >> 10];
        rowptr[i] = base;
        int run = base;
        int ind = 1;  // self loop
        #pragma unroll
        for (int r = 0; r < KREP; ++r) {
            cursor_rep[r * NPAD + i] = run;
            run += outdeg_rep[r * NPAD + i];
            ind += indeg_rep[r * NPAD + i];
        }
        dinv[i] = rsqrtf((float)ind);
    }
}

// Bucket edges by src using the replica cursor matching count's r = e & 7.
__global__ void scatter_kernel(const int* __restrict__ idx, int* __restrict__ cursor_rep,
                               int* __restrict__ dst_sorted) {
    int e = blockIdx.x * blockDim.x + threadIdx.x;
    if (e < EE) {
        int r = e & (KREP - 1);
        int s = idx[e], d = idx[EE + e];
        int pos = atomicAdd(&cursor_rep[r * NPAD + s], 1);
        dst_sorted[pos] = d;
    }
}

// ---------- per-hop gather ----------

// One 64-lane wave per row; halves process even/odd edges; cross-half shuffle reduce.
// out[i] = 0.9*dinv[i]*sum_e dinv[dst_e]*cur[dst_e] + (0.9*dinv[i]^2 + 0.1)*cur[i]
__global__ void gather_x_kernel(const int* __restrict__ rowptr, const int* __restrict__ dst_sorted,
                                const float* __restrict__ dinv, const float4* __restrict__ cur,
                                float4* __restrict__ next) {
    int t = blockIdx.x * blockDim.x + threadIdx.x;
    int row = t >> 6;
    int lane = t & 63;
    int half = lane >> 5;
    int sub = lane & 31;
    if (row >= NN) return;
    int beg = rowptr[row], end = rowptr[row + 1];
    float4 acc = make_float4(0.f, 0.f, 0.f, 0.f);
    for (int e = beg + half; e < end; e += 2) {
        int d = dst_sorted[e];
        float dv = dinv[d];
        float4 v = cur[(size_t)d * 32 + sub];
        acc.x += dv * v.x;
        acc.y += dv * v.y;
        acc.z += dv * v.z;
        acc.w += dv * v.w;
    }
    acc.x += __shfl_xor(acc.x, 32);
    acc.y += __shfl_xor(acc.y, 32);
    acc.z += __shfl_xor(acc.z, 32);
    acc.w += __shfl_xor(acc.w, 32);
    if (half == 0) {
        float di = dinv[row];
        float sg = 0.9f * di;
        float sl = 0.9f * di * di + 0.1f;
        float4 c = cur[(size_t)row * 32 + sub];
        float4 r;
        r.x = sg * acc.x + sl * c.x;
        r.y = sg * acc.y + sl * c.y;
        r.z = sg * acc.z + sl * c.z;
        r.w = sg * acc.w + sl * c.w;
        next[(size_t)row * 32 + sub] = r;
    }
}

// One 64-lane wave per row; 8 edge-groups x 8 column-lanes; 3-step shuffle reduce.
__global__ void gather_y_kernel(const int* __restrict__ rowptr, const int* __restrict__ dst_sorted,
                                const float* __restrict__ dinv, const float4* __restrict__ cur,
                                float4* __restrict__ next) {
    int t = blockIdx.x * blockDim.x + threadIdx.x;
    int row = t >> 6;
    int lane = t & 63;
    int grp = lane >> 3;
    int sub = lane & 7;
    if (row >= NN) return;
    int beg = rowptr[row], end = rowptr[row + 1];
    float4 acc = make_float4(0.f, 0.f, 0.f, 0.f);
    for (int e = beg + grp; e < end; e += 8) {
        int d = dst_sorted[e];
        float dv = dinv[d];
        float4 v = cur[(size_t)d * 8 + sub];
        acc.x += dv * v.x;
        acc.y += dv * v.y;
        acc.z += dv * v.z;
        acc.w += dv * v.w;
    }
    #pragma unroll
    for (int m = 8; m <= 32; m <<= 1) {
        acc.x += __shfl_xor(acc.x, m);
        acc.y += __shfl_xor(acc.y, m);
        acc.z += __shfl_xor(acc.z, m);
        acc.w += __shfl_xor(acc.w, m);
    }
    if (grp == 0) {
        float di = dinv[row];
        float sg = 0.9f * di;
        float sl = 0.9f * di * di + 0.1f;
        float4 c = cur[(size_t)row * 8 + sub];
        float4 r;
        r.x = sg * acc.x + sl * c.x;
        r.y = sg * acc.y + sl * c.y;
        r.z = sg * acc.z + sl * c.z;
        r.w = sg * acc.w + sl * c.w;
        next[(size_t)row * 8 + sub] = r;
    }
}

extern "C" void kernel_launch(void* const* d_in, const int* in_sizes, int n_in,
                              void* d_out, int out_size, void* d_ws, size_t ws_size,
                              hipStream_t stream) {
    const float* x0  = (const float*)d_in[0];
    const float* y0  = (const float*)d_in[1];
    const void*  raw = d_in[2];   // [2,E] flattened, int32 or int64 (detected on device)

    float* out_x = (float*)d_out;
    float* out_y = out_x + (size_t)NN * DXX;

    // ws layout (4-byte units):
    // flag[16] | idx[2E] | indeg_rep[K*NPAD] | outdeg_rep[K*NPAD] | cursor_rep[K*NPAD]
    // | rowptr[NN+1 pad] | blocksums[128] | dinv[NPAD] | dst_sorted[E] | xA[N*DX] | yA[N*DY]
    int*   flag       = (int*)d_ws;
    int*   idx        = flag + 16;
    int*   indeg_rep  = idx + 2 * EE;
    int*   outdeg_rep = indeg_rep + KREP * NPAD;
    int*   cursor_rep = outdeg_rep + KREP * NPAD;
    int*   rowptr     = cursor_rep + KREP * NPAD;
    int*   blocksums  = rowptr + 100112;
    float* dinv       = (float*)(blocksums + 128);
    int*   dst_sorted = (int*)(dinv + NPAD);
    float* xA         = (float*)(dst_sorted + EE);
    float* yA         = xA + (size_t)NN * DXX;

    const int B = 256;

    detect_kernel<<<1, 64, 0, stream>>>((const int*)raw, flag);
    convert_kernel<<<(2 * EE + B - 1) / B, B, 0, stream>>>(raw, flag, idx);
    zero_kernel<<<(2 * KREP * NPAD + B - 1) / B, B, 0, stream>>>(indeg_rep);
    count_kernel<<<(EE + B - 1) / B, B, 0, stream>>>(idx, indeg_rep, outdeg_rep);
    scan1_kernel<<<NB, SCAN_B, 0, stream>>>(outdeg_rep, rowptr, blocksums);
    scan2_kernel<<<1, 128, 0, stream>>>(blocksums, rowptr);
    scan3_kernel<<<(NN + B - 1) / B, B, 0, stream>>>(rowptr, blocksums, indeg_rep,
                                                    outdeg_rep, cursor_rep, dinv);
    scatter_kernel<<<(EE + B - 1) / B, B, 0, stream>>>(idx, cursor_rep, dst_sorted);

    const float* xc = x0;
    const float* yc = y0;
    for (int h = 0; h < 4; ++h) {
        // ping-pong: h=0 -> ws, h=1 -> d_out, h=2 -> ws, h=3 -> d_out (final lands in d_out)
        float* xn = (h & 1) ? out_x : xA;
        float* yn = (h & 1) ? out_y : yA;

        gather_x_kernel<<<(NN * 64 + B - 1) / B, B, 0, stream>>>(
            rowptr, dst_sorted, dinv, (const float4*)xc, (float4*)xn);
        gather_y_kernel<<<(NN * 64 + B - 1) / B, B, 0, stream>>>(
            rowptr, dst_sorted, dinv, (const float4*)yc, (float4*)yn);

        xc = xn;
        yc = yn;
    }
}

// Round 5
// 858.977 us; speedup vs baseline: 15.6923x; 1.2101x over previous
//
#include <hip/hip_runtime.h>

// APPNP-style propagation: 4 hops of M = 0.9*A_hat + 0.1*I on x[N,128], y[N,32].
// Round 5: bf16 intermediate iterates (fp32 accumulate). Halves gather traffic and
// shrinks working set; hop1 reads fp32 inputs, hop4 writes fp32 to d_out.
// gather_x: 4x16-lane subgroups (4 edges in flight); gather_y: 16x4-lane (16 edges).

#define NN 100000
#define EE 1600000
#define NPAD 100096     // N padded to multiple of 64
#define KREP 8
#define SCAN_B 1024
#define NB 98           // ceil(NN / SCAN_B)

// ---------- bf16 helpers (RNE) ----------
__device__ __forceinline__ float bflo(unsigned w) { return __uint_as_float(w << 16); }
__device__ __forceinline__ float bfhi(unsigned w) { return __uint_as_float(w & 0xffff0000u); }
__device__ __forceinline__ unsigned packbf(float a, float b) {
    unsigned ua = __float_as_uint(a), ub = __float_as_uint(b);
    unsigned ra = (ua + 0x7fffu + ((ua >> 16) & 1u)) >> 16;
    unsigned rb = (ub + 0x7fffu + ((ub >> 16) & 1u)) >> 16;
    return ra | (rb << 16);
}

// ---------- preprocessing ----------

__global__ void detect_kernel(const int* __restrict__ raw, int* __restrict__ flag) {
    if (threadIdx.x == 0 && blockIdx.x == 0) {
        int is64 = 1;
        for (int k = 1; k < 16; k += 2) {
            if (raw[k] != 0) { is64 = 0; break; }
        }
        *flag = is64;
    }
}

__global__ void convert_kernel(const void* __restrict__ raw, const int* __restrict__ flag,
                               int* __restrict__ idx) {
    int e = blockIdx.x * blockDim.x + threadIdx.x;
    if (e < 2 * EE) {
        if (*flag) idx[e] = (int)((const long long*)raw)[e];
        else       idx[e] = ((const int*)raw)[e];
    }
}

__global__ void zero_kernel(int* __restrict__ bufs) {
    int i = blockIdx.x * blockDim.x + threadIdx.x;
    if (i < 2 * KREP * NPAD) bufs[i] = 0;
}

__global__ void count_kernel(const int* __restrict__ idx, int* __restrict__ indeg_rep,
                             int* __restrict__ outdeg_rep) {
    int e = blockIdx.x * blockDim.x + threadIdx.x;
    if (e < EE) {
        int r = e & (KREP - 1);
        int s = idx[e], d = idx[EE + e];
        atomicAdd(&outdeg_rep[r * NPAD + s], 1);
        atomicAdd(&indeg_rep[r * NPAD + d], 1);
    }
}

__global__ void scan1_kernel(const int* __restrict__ outdeg_rep, int* __restrict__ rowptr,
                             int* __restrict__ blocksums) {
    __shared__ int s[SCAN_B];
    int tid = threadIdx.x;
    int gid = blockIdx.x * SCAN_B + tid;
    int od = 0;
    if (gid < NN) {
        #pragma unroll
        for (int r = 0; r < KREP; ++r) od += outdeg_rep[r * NPAD + gid];
    }
    s[tid] = od;
    __syncthreads();
    for (int off = 1; off < SCAN_B; off <<= 1) {
        int t = (tid >= off) ? s[tid - off] : 0;
        __syncthreads();
        s[tid] += t;
        __syncthreads();
    }
    if (gid < NN) rowptr[gid] = s[tid] - od;
    if (tid == SCAN_B - 1) blocksums[blockIdx.x] = s[tid];
}

__global__ void scan2_kernel(int* __restrict__ blocksums, int* __restrict__ rowptr) {
    __shared__ int s[128];
    int tid = threadIdx.x;
    int v = (tid < NB) ? blocksums[tid] : 0;
    s[tid] = v;
    __syncthreads();
    for (int off = 1; off < 128; off <<= 1) {
        int t = (tid >= off) ? s[tid - off] : 0;
        __syncthreads();
        s[tid] += t;
        __syncthreads();
    }
    if (tid < NB) blocksums[tid] = s[tid] - v;
    if (tid == 0) rowptr[NN] = EE;
}

__global__ void scan3_kernel(int* __restrict__ rowptr, const int* __restrict__ blocksums,
                             const int* __restrict__ indeg_rep, const int* __restrict__ outdeg_rep,
                             int* __restrict__ cursor_rep, float* __restrict__ dinv) {
    int i = blockIdx.x * blockDim.x + threadIdx.x;
    if (i < NN) {
        int base = rowptr[i] + blocksums[i >> 10];
        rowptr[i] = base;
        int run = base;
        int ind = 1;  // self loop
        #pragma unroll
        for (int r = 0; r < KREP; ++r) {
            cursor_rep[r * NPAD + i] = run;
            run += outdeg_rep[r * NPAD + i];
            ind += indeg_rep[r * NPAD + i];
        }
        dinv[i] = rsqrtf((float)ind);
    }
}

__global__ void scatter_kernel(const int* __restrict__ idx, int* __restrict__ cursor_rep,
                               int* __restrict__ dst_sorted) {
    int e = blockIdx.x * blockDim.x + threadIdx.x;
    if (e < EE) {
        int r = e & (KREP - 1);
        int s = idx[e], d = idx[EE + e];
        int pos = atomicAdd(&cursor_rep[r * NPAD + s], 1);
        dst_sorted[pos] = d;
    }
}

// ---------- per-hop gather ----------

// x: one 64-lane wave per row; 4 subgroups of 16 lanes; each lane owns 8 columns.
// out[i] = 0.9*dinv[i]*sum_e dinv[d_e]*cur[d_e] + (0.9*dinv[i]^2 + 0.1)*cur[i]
template <bool INBF, bool OUTBF>
__global__ void gather_x_t(const int* __restrict__ rowptr, const int* __restrict__ dst_sorted,
                           const float* __restrict__ dinv, const void* __restrict__ cur,
                           void* __restrict__ next) {
    int t = blockIdx.x * blockDim.x + threadIdx.x;
    int row = t >> 6, lane = t & 63, g = lane >> 4, sub = lane & 15;
    if (row >= NN) return;
    int beg = rowptr[row], end = rowptr[row + 1];
    const uint4*  curb = (const uint4*)cur;
    const float4* curf = (const float4*)cur;
    float acc[8] = {0.f, 0.f, 0.f, 0.f, 0.f, 0.f, 0.f, 0.f};
    for (int e = beg + g; e < end; e += 4) {
        int d = dst_sorted[e];
        float dv = dinv[d];
        if constexpr (INBF) {
            uint4 w = curb[(size_t)d * 16 + sub];
            acc[0] += dv * bflo(w.x); acc[1] += dv * bfhi(w.x);
            acc[2] += dv * bflo(w.y); acc[3] += dv * bfhi(w.y);
            acc[4] += dv * bflo(w.z); acc[5] += dv * bfhi(w.z);
            acc[6] += dv * bflo(w.w); acc[7] += dv * bfhi(w.w);
        } else {
            float4 a = curf[(size_t)d * 32 + sub * 2];
            float4 b = curf[(size_t)d * 32 + sub * 2 + 1];
            acc[0] += dv * a.x; acc[1] += dv * a.y; acc[2] += dv * a.z; acc[3] += dv * a.w;
            acc[4] += dv * b.x; acc[5] += dv * b.y; acc[6] += dv * b.z; acc[7] += dv * b.w;
        }
    }
    #pragma unroll
    for (int m = 16; m <= 32; m <<= 1) {
        #pragma unroll
        for (int i = 0; i < 8; ++i) acc[i] += __shfl_xor(acc[i], m);
    }
    if (g == 0) {
        float di = dinv[row];
        float sg = 0.9f * di, sl = 0.9f * di * di + 0.1f;
        float c[8];
        if constexpr (INBF) {
            uint4 w = curb[(size_t)row * 16 + sub];
            c[0] = bflo(w.x); c[1] = bfhi(w.x); c[2] = bflo(w.y); c[3] = bfhi(w.y);
            c[4] = bflo(w.z); c[5] = bfhi(w.z); c[6] = bflo(w.w); c[7] = bfhi(w.w);
        } else {
            float4 a = curf[(size_t)row * 32 + sub * 2];
            float4 b = curf[(size_t)row * 32 + sub * 2 + 1];
            c[0] = a.x; c[1] = a.y; c[2] = a.z; c[3] = a.w;
            c[4] = b.x; c[5] = b.y; c[6] = b.z; c[7] = b.w;
        }
        float r[8];
        #pragma unroll
        for (int i = 0; i < 8; ++i) r[i] = sg * acc[i] + sl * c[i];
        if constexpr (OUTBF) {
            uint4 o;
            o.x = packbf(r[0], r[1]); o.y = packbf(r[2], r[3]);
            o.z = packbf(r[4], r[5]); o.w = packbf(r[6], r[7]);
            ((uint4*)next)[(size_t)row * 16 + sub] = o;
        } else {
            float4 a, b;
            a.x = r[0]; a.y = r[1]; a.z = r[2]; a.w = r[3];
            b.x = r[4]; b.y = r[5]; b.z = r[6]; b.w = r[7];
            ((float4*)next)[(size_t)row * 32 + sub * 2]     = a;
            ((float4*)next)[(size_t)row * 32 + sub * 2 + 1] = b;
        }
    }
}

// y: one 64-lane wave per row; 16 subgroups of 4 lanes; each lane owns 8 columns.
template <bool INBF, bool OUTBF>
__global__ void gather_y_t(const int* __restrict__ rowptr, const int* __restrict__ dst_sorted,
                           const float* __restrict__ dinv, const void* __restrict__ cur,
                           void* __restrict__ next) {
    int t = blockIdx.x * blockDim.x + threadIdx.x;
    int row = t >> 6, lane = t & 63, g = lane >> 2, sub = lane & 3;
    if (row >= NN) return;
    int beg = rowptr[row], end = rowptr[row + 1];
    const uint4*  curb = (const uint4*)cur;
    const float4* curf = (const float4*)cur;
    float acc[8] = {0.f, 0.f, 0.f, 0.f, 0.f, 0.f, 0.f, 0.f};
    for (int e = beg + g; e < end; e += 16) {
        int d = dst_sorted[e];
        float dv = dinv[d];
        if constexpr (INBF) {
            uint4 w = curb[(size_t)d * 4 + sub];
            acc[0] += dv * bflo(w.x); acc[1] += dv * bfhi(w.x);
            acc[2] += dv * bflo(w.y); acc[3] += dv * bfhi(w.y);
            acc[4] += dv * bflo(w.z); acc[5] += dv * bfhi(w.z);
            acc[6] += dv * bflo(w.w); acc[7] += dv * bfhi(w.w);
        } else {
            float4 a = curf[(size_t)d * 8 + sub * 2];
            float4 b = curf[(size_t)d * 8 + sub * 2 + 1];
            acc[0] += dv * a.x; acc[1] += dv * a.y; acc[2] += dv * a.z; acc[3] += dv * a.w;
            acc[4] += dv * b.x; acc[5] += dv * b.y; acc[6] += dv * b.z; acc[7] += dv * b.w;
        }
    }
    #pragma unroll
    for (int m = 4; m <= 32; m <<= 1) {
        #pragma unroll
        for (int i = 0; i < 8; ++i) acc[i] += __shfl_xor(acc[i], m);
    }
    if (g == 0) {
        float di = dinv[row];
        float sg = 0.9f * di, sl = 0.9f * di * di + 0.1f;
        float c[8];
        if constexpr (INBF) {
            uint4 w = curb[(size_t)row * 4 + sub];
            c[0] = bflo(w.x); c[1] = bfhi(w.x); c[2] = bflo(w.y); c[3] = bfhi(w.y);
            c[4] = bflo(w.z); c[5] = bfhi(w.z); c[6] = bflo(w.w); c[7] = bfhi(w.w);
        } else {
            float4 a = curf[(size_t)row * 8 + sub * 2];
            float4 b = curf[(size_t)row * 8 + sub * 2 + 1];
            c[0] = a.x; c[1] = a.y; c[2] = a.z; c[3] = a.w;
            c[4] = b.x; c[5] = b.y; c[6] = b.z; c[7] = b.w;
        }
        float r[8];
        #pragma unroll
        for (int i = 0; i < 8; ++i) r[i] = sg * acc[i] + sl * c[i];
        if constexpr (OUTBF) {
            uint4 o;
            o.x = packbf(r[0], r[1]); o.y = packbf(r[2], r[3]);
            o.z = packbf(r[4], r[5]); o.w = packbf(r[6], r[7]);
            ((uint4*)next)[(size_t)row * 4 + sub] = o;
        } else {
            float4 a, b;
            a.x = r[0]; a.y = r[1]; a.z = r[2]; a.w = r[3];
            b.x = r[4]; b.y = r[5]; b.z = r[6]; b.w = r[7];
            ((float4*)next)[(size_t)row * 8 + sub * 2]     = a;
            ((float4*)next)[(size_t)row * 8 + sub * 2 + 1] = b;
        }
    }
}

extern "C" void kernel_launch(void* const* d_in, const int* in_sizes, int n_in,
                              void* d_out, int out_size, void* d_ws, size_t ws_size,
                              hipStream_t stream) {
    const float* x0  = (const float*)d_in[0];
    const float* y0  = (const float*)d_in[1];
    const void*  raw = d_in[2];

    float* out_x = (float*)d_out;
    float* out_y = out_x + (size_t)NN * 128;

    // ws layout (4-byte units):
    // flag[16] | idx[2E] | indeg_rep[K*NPAD] | outdeg_rep[K*NPAD] | cursor_rep[K*NPAD]
    // | rowptr[100112] | blocksums[128] | dinv[NPAD] | dst_sorted[E]
    // | xbA[N*64] | xbB[N*64] | ybA[N*16] | ybB[N*16]   (bf16 buffers)  ~= 94 MB
    int*   flag       = (int*)d_ws;
    int*   idx        = flag + 16;
    int*   indeg_rep  = idx + 2 * EE;
    int*   outdeg_rep = indeg_rep + KREP * NPAD;
    int*   cursor_rep = outdeg_rep + KREP * NPAD;
    int*   rowptr     = cursor_rep + KREP * NPAD;
    int*   blocksums  = rowptr + 100112;
    float* dinv       = (float*)(blocksums + 128);
    int*   dst_sorted = (int*)(dinv + NPAD);
    int*   xbA        = dst_sorted + EE;
    int*   xbB        = xbA + (size_t)NN * 64;
    int*   ybA        = xbB + (size_t)NN * 64;
    int*   ybB        = ybA + (size_t)NN * 16;

    const int B = 256;
    const int GW = (NN * 64 + B - 1) / B;   // one wave per row

    detect_kernel<<<1, 64, 0, stream>>>((const int*)raw, flag);
    convert_kernel<<<(2 * EE + B - 1) / B, B, 0, stream>>>(raw, flag, idx);
    zero_kernel<<<(2 * KREP * NPAD + B - 1) / B, B, 0, stream>>>(indeg_rep);
    count_kernel<<<(EE + B - 1) / B, B, 0, stream>>>(idx, indeg_rep, outdeg_rep);
    scan1_kernel<<<NB, SCAN_B, 0, stream>>>(outdeg_rep, rowptr, blocksums);
    scan2_kernel<<<1, 128, 0, stream>>>(blocksums, rowptr);
    scan3_kernel<<<(NN + B - 1) / B, B, 0, stream>>>(rowptr, blocksums, indeg_rep,
                                                    outdeg_rep, cursor_rep, dinv);
    scatter_kernel<<<(EE + B - 1) / B, B, 0, stream>>>(idx, cursor_rep, dst_sorted);

    // hop 1: fp32 in -> bf16 out
    gather_x_t<false, true><<<GW, B, 0, stream>>>(rowptr, dst_sorted, dinv, x0, xbA);
    gather_y_t<false, true><<<GW, B, 0, stream>>>(rowptr, dst_sorted, dinv, y0, ybA);
    // hop 2: bf16 -> bf16
    gather_x_t<true, true><<<GW, B, 0, stream>>>(rowptr, dst_sorted, dinv, xbA, xbB);
    gather_y_t<true, true><<<GW, B, 0, stream>>>(rowptr, dst_sorted, dinv, ybA, ybB);
    // hop 3: bf16 -> bf16
    gather_x_t<true, true><<<GW, B, 0, stream>>>(rowptr, dst_sorted, dinv, xbB, xbA);
    gather_y_t<true, true><<<GW, B, 0, stream>>>(rowptr, dst_sorted, dinv, ybB, ybA);
    // hop 4: bf16 -> fp32 (d_out)
    gather_x_t<true, false><<<GW, B, 0, stream>>>(rowptr, dst_sorted, dinv, xbA, out_x);
    gather_y_t<true, false><<<GW, B, 0, stream>>>(rowptr, dst_sorted, dinv, ybA, out_y);
}

// Round 6
// 749.834 us; speedup vs baseline: 17.9764x; 1.1456x over previous
//
#include <hip/hip_runtime.h>

// APPNP-style propagation: 4 hops of M = 0.9*A_hat + 0.1*I on x[N,128], y[N,32].
// Round 6: preprocessing rebuilt as XCD-local two-pass bucket sort.
//  passA: raw edges -> replicated indeg atomics + append pack(src&255,dst) to
//         (bucket = src>>8, replica = blockIdx&7 ~ XCD) region. Sequential per-stream
//         writes kill the 17x write amplification seen in Round 5's scatter.
//  passB: one WG per bucket: LDS stage -> LDS histogram -> LDS scan -> rowptr +
//         contiguous dst_sorted slice. Replaces count(outdeg)/scan1/scan2/scan3/scatter.
// Gathers unchanged from Round 5 (bf16 intermediates, fp32 accumulate).

#define NN 100000
#define EE 1600000
#define NPAD 100096     // N padded to multiple of 64
#define NBKT 391        // ceil(NN/256); bucket = src >> 8
#define CAP 1024        // per-(bucket,replica) region capacity (mean 512, +22 sigma)

// ---------- bf16 helpers (RNE) ----------
__device__ __forceinline__ float bflo(unsigned w) { return __uint_as_float(w << 16); }
__device__ __forceinline__ float bfhi(unsigned w) { return __uint_as_float(w & 0xffff0000u); }
__device__ __forceinline__ unsigned packbf(float a, float b) {
    unsigned ua = __float_as_uint(a), ub = __float_as_uint(b);
    unsigned ra = (ua + 0x7fffu + ((ua >> 16) & 1u)) >> 16;
    unsigned rb = (ub + 0x7fffu + ((ub >> 16) & 1u)) >> 16;
    return ra | (rb << 16);
}

// ---------- preprocessing ----------

__global__ void detect_kernel(const int* __restrict__ raw, int* __restrict__ flag) {
    if (threadIdx.x == 0 && blockIdx.x == 0) {
        int is64 = 1;
        for (int k = 1; k < 16; k += 2) {
            if (raw[k] != 0) { is64 = 0; break; }
        }
        *flag = is64;
    }
}

// zero indeg_rep[8*NPAD] + bcur[4096] (contiguous)
__global__ void zero_kernel(int* __restrict__ bufs, int total) {
    int i = blockIdx.x * blockDim.x + threadIdx.x;
    if (i < total) bufs[i] = 0;
}

// One pass over edges: indeg atomics + bucket append. replica = blockIdx&7 (~XCD id)
// keeps each (bucket,replica) write stream and its cursor line XCD-local.
__global__ void passA_kernel(const void* __restrict__ raw, const int* __restrict__ flag,
                             int* __restrict__ indeg_rep, int* __restrict__ bcur,
                             int* __restrict__ buf) {
    int e = blockIdx.x * blockDim.x + threadIdx.x;
    int r = blockIdx.x & 7;
    if (e < EE) {
        int s, d;
        if (*flag) {
            s = (int)((const long long*)raw)[e];
            d = (int)((const long long*)raw)[EE + e];
        } else {
            s = ((const int*)raw)[e];
            d = ((const int*)raw)[EE + e];
        }
        atomicAdd(&indeg_rep[r * NPAD + d], 1);
        int b = s >> 8;
        int pos = atomicAdd(&bcur[r * 512 + b], 1);   // replica-major: replicas on separate lines
        if (pos < CAP)
            buf[((size_t)(r * NBKT + b)) * CAP + pos] = ((s & 255) << 17) | d;   // d < 2^17
    }
}

// Exclusive prefix over bucket totals -> bucket_base; set rowptr[NN]=EE.
__global__ void bucket_scan_kernel(const int* __restrict__ bcur, int* __restrict__ bucket_base,
                                   int* __restrict__ rowptr) {
    __shared__ int s[512];
    int tid = threadIdx.x;
    int v = 0;
    if (tid < NBKT) {
        #pragma unroll
        for (int r = 0; r < 8; ++r) {
            int c = bcur[r * 512 + tid];
            v += (c < CAP) ? c : CAP;
        }
    }
    s[tid] = v;
    __syncthreads();
    for (int off = 1; off < 512; off <<= 1) {
        int t = (tid >= off) ? s[tid - off] : 0;
        __syncthreads();
        s[tid] += t;
        __syncthreads();
    }
    if (tid < NBKT) bucket_base[tid] = s[tid] - v;
    if (tid == 0) rowptr[NN] = EE;
}

// dinv[i] = rsqrt(1 + sum_r indeg_rep[r][i])
__global__ void dinv_kernel(const int* __restrict__ indeg_rep, float* __restrict__ dinv) {
    int i = blockIdx.x * blockDim.x + threadIdx.x;
    if (i < NN) {
        int ind = 1;
        #pragma unroll
        for (int r = 0; r < 8; ++r) ind += indeg_rep[r * NPAD + i];
        dinv[i] = rsqrtf((float)ind);
    }
}

// One WG (256 thr) per bucket: stage edges in LDS, histogram 256 local nodes,
// prefix scan, write rowptr + scatter dst into contiguous dst_sorted slice.
__global__ __launch_bounds__(256) void passB_kernel(const int* __restrict__ bcur,
                                                    const int* __restrict__ buf,
                                                    const int* __restrict__ bucket_base,
                                                    int* __restrict__ rowptr,
                                                    int* __restrict__ dst_sorted) {
    int b = blockIdx.x;
    int tid = threadIdx.x;
    __shared__ int cnt[8], off[9];
    __shared__ int edges[8 * CAP];      // 32 KB
    __shared__ int hist[256];
    __shared__ int sc[256];
    __shared__ int base_s;

    if (tid < 8) {
        int c = bcur[tid * 512 + b];
        cnt[tid] = (c < CAP) ? c : CAP;
    }
    hist[tid] = 0;
    __syncthreads();
    if (tid == 0) {
        int run = 0;
        #pragma unroll
        for (int r = 0; r < 8; ++r) { off[r] = run; run += cnt[r]; }
        off[8] = run;
        base_s = bucket_base[b];
    }
    __syncthreads();
    // stage the 8 regions into LDS (concatenated)
    #pragma unroll
    for (int r = 0; r < 8; ++r) {
        int c = cnt[r];
        const int* src = buf + ((size_t)(r * NBKT + b)) * CAP;
        for (int i = tid; i < c; i += 256) edges[off[r] + i] = src[i];
    }
    __syncthreads();
    int total = off[8];
    // histogram over local src
    for (int i = tid; i < total; i += 256) atomicAdd(&hist[edges[i] >> 17], 1);
    __syncthreads();
    // exclusive scan of hist
    int hv = hist[tid];
    sc[tid] = hv;
    __syncthreads();
    for (int o = 1; o < 256; o <<= 1) {
        int t = (tid >= o) ? sc[tid - o] : 0;
        __syncthreads();
        sc[tid] += t;
        __syncthreads();
    }
    int excl = sc[tid] - hv;
    int node = (b << 8) + tid;
    if (node < NN) rowptr[node] = base_s + excl;
    hist[tid] = excl;   // reuse as cursor
    __syncthreads();
    // scatter into the bucket's contiguous slice (XCD-local, ~16 KB)
    for (int i = tid; i < total; i += 256) {
        int p = edges[i];
        int pos = atomicAdd(&hist[p >> 17], 1);
        dst_sorted[base_s + pos] = p & 0x1ffff;
    }
}

// ---------- per-hop gather (unchanged from Round 5) ----------

template <bool INBF, bool OUTBF>
__global__ void gather_x_t(const int* __restrict__ rowptr, const int* __restrict__ dst_sorted,
                           const float* __restrict__ dinv, const void* __restrict__ cur,
                           void* __restrict__ next) {
    int t = blockIdx.x * blockDim.x + threadIdx.x;
    int row = t >> 6, lane = t & 63, g = lane >> 4, sub = lane & 15;
    if (row >= NN) return;
    int beg = rowptr[row], end = rowptr[row + 1];
    const uint4*  curb = (const uint4*)cur;
    const float4* curf = (const float4*)cur;
    float acc[8] = {0.f, 0.f, 0.f, 0.f, 0.f, 0.f, 0.f, 0.f};
    for (int e = beg + g; e < end; e += 4) {
        int d = dst_sorted[e];
        float dv = dinv[d];
        if constexpr (INBF) {
            uint4 w = curb[(size_t)d * 16 + sub];
            acc[0] += dv * bflo(w.x); acc[1] += dv * bfhi(w.x);
            acc[2] += dv * bflo(w.y); acc[3] += dv * bfhi(w.y);
            acc[4] += dv * bflo(w.z); acc[5] += dv * bfhi(w.z);
            acc[6] += dv * bflo(w.w); acc[7] += dv * bfhi(w.w);
        } else {
            float4 a = curf[(size_t)d * 32 + sub * 2];
            float4 b2 = curf[(size_t)d * 32 + sub * 2 + 1];
            acc[0] += dv * a.x; acc[1] += dv * a.y; acc[2] += dv * a.z; acc[3] += dv * a.w;
            acc[4] += dv * b2.x; acc[5] += dv * b2.y; acc[6] += dv * b2.z; acc[7] += dv * b2.w;
        }
    }
    #pragma unroll
    for (int m = 16; m <= 32; m <<= 1) {
        #pragma unroll
        for (int i = 0; i < 8; ++i) acc[i] += __shfl_xor(acc[i], m);
    }
    if (g == 0) {
        float di = dinv[row];
        float sg = 0.9f * di, sl = 0.9f * di * di + 0.1f;
        float c[8];
        if constexpr (INBF) {
            uint4 w = curb[(size_t)row * 16 + sub];
            c[0] = bflo(w.x); c[1] = bfhi(w.x); c[2] = bflo(w.y); c[3] = bfhi(w.y);
            c[4] = bflo(w.z); c[5] = bfhi(w.z); c[6] = bflo(w.w); c[7] = bfhi(w.w);
        } else {
            float4 a = curf[(size_t)row * 32 + sub * 2];
            float4 b2 = curf[(size_t)row * 32 + sub * 2 + 1];
            c[0] = a.x; c[1] = a.y; c[2] = a.z; c[3] = a.w;
            c[4] = b2.x; c[5] = b2.y; c[6] = b2.z; c[7] = b2.w;
        }
        float r[8];
        #pragma unroll
        for (int i = 0; i < 8; ++i) r[i] = sg * acc[i] + sl * c[i];
        if constexpr (OUTBF) {
            uint4 o;
            o.x = packbf(r[0], r[1]); o.y = packbf(r[2], r[3]);
            o.z = packbf(r[4], r[5]); o.w = packbf(r[6], r[7]);
            ((uint4*)next)[(size_t)row * 16 + sub] = o;
        } else {
            float4 a, b2;
            a.x = r[0]; a.y = r[1]; a.z = r[2]; a.w = r[3];
            b2.x = r[4]; b2.y = r[5]; b2.z = r[6]; b2.w = r[7];
            ((float4*)next)[(size_t)row * 32 + sub * 2]     = a;
            ((float4*)next)[(size_t)row * 32 + sub * 2 + 1] = b2;
        }
    }
}

template <bool INBF, bool OUTBF>
__global__ void gather_y_t(const int* __restrict__ rowptr, const int* __restrict__ dst_sorted,
                           const float* __restrict__ dinv, const void* __restrict__ cur,
                           void* __restrict__ next) {
    int t = blockIdx.x * blockDim.x + threadIdx.x;
    int row = t >> 6, lane = t & 63, g = lane >> 2, sub = lane & 3;
    if (row >= NN) return;
    int beg = rowptr[row], end = rowptr[row + 1];
    const uint4*  curb = (const uint4*)cur;
    const float4* curf = (const float4*)cur;
    float acc[8] = {0.f, 0.f, 0.f, 0.f, 0.f, 0.f, 0.f, 0.f};
    for (int e = beg + g; e < end; e += 16) {
        int d = dst_sorted[e];
        float dv = dinv[d];
        if constexpr (INBF) {
            uint4 w = curb[(size_t)d * 4 + sub];
            acc[0] += dv * bflo(w.x); acc[1] += dv * bfhi(w.x);
            acc[2] += dv * bflo(w.y); acc[3] += dv * bfhi(w.y);
            acc[4] += dv * bflo(w.z); acc[5] += dv * bfhi(w.z);
            acc[6] += dv * bflo(w.w); acc[7] += dv * bfhi(w.w);
        } else {
            float4 a = curf[(size_t)d * 8 + sub * 2];
            float4 b2 = curf[(size_t)d * 8 + sub * 2 + 1];
            acc[0] += dv * a.x; acc[1] += dv * a.y; acc[2] += dv * a.z; acc[3] += dv * a.w;
            acc[4] += dv * b2.x; acc[5] += dv * b2.y; acc[6] += dv * b2.z; acc[7] += dv * b2.w;
        }
    }
    #pragma unroll
    for (int m = 4; m <= 32; m <<= 1) {
        #pragma unroll
        for (int i = 0; i < 8; ++i) acc[i] += __shfl_xor(acc[i], m);
    }
    if (g == 0) {
        float di = dinv[row];
        float sg = 0.9f * di, sl = 0.9f * di * di + 0.1f;
        float c[8];
        if constexpr (INBF) {
            uint4 w = curb[(size_t)row * 4 + sub];
            c[0] = bflo(w.x); c[1] = bfhi(w.x); c[2] = bflo(w.y); c[3] = bfhi(w.y);
            c[4] = bflo(w.z); c[5] = bfhi(w.z); c[6] = bflo(w.w); c[7] = bfhi(w.w);
        } else {
            float4 a = curf[(size_t)row * 8 + sub * 2];
            float4 b2 = curf[(size_t)row * 8 + sub * 2 + 1];
            c[0] = a.x; c[1] = a.y; c[2] = a.z; c[3] = a.w;
            c[4] = b2.x; c[5] = b2.y; c[6] = b2.z; c[7] = b2.w;
        }
        float r[8];
        #pragma unroll
        for (int i = 0; i < 8; ++i) r[i] = sg * acc[i] + sl * c[i];
        if constexpr (OUTBF) {
            uint4 o;
            o.x = packbf(r[0], r[1]); o.y = packbf(r[2], r[3]);
            o.z = packbf(r[4], r[5]); o.w = packbf(r[6], r[7]);
            ((uint4*)next)[(size_t)row * 4 + sub] = o;
        } else {
            float4 a, b2;
            a.x = r[0]; a.y = r[1]; a.z = r[2]; a.w = r[3];
            b2.x = r[4]; b2.y = r[5]; b2.z = r[6]; b2.w = r[7];
            ((float4*)next)[(size_t)row * 8 + sub * 2]     = a;
            ((float4*)next)[(size_t)row * 8 + sub * 2 + 1] = b2;
        }
    }
}

extern "C" void kernel_launch(void* const* d_in, const int* in_sizes, int n_in,
                              void* d_out, int out_size, void* d_ws, size_t ws_size,
                              hipStream_t stream) {
    const float* x0  = (const float*)d_in[0];
    const float* y0  = (const float*)d_in[1];
    const void*  raw = d_in[2];

    float* out_x = (float*)d_out;
    float* out_y = out_x + (size_t)NN * 128;

    // ws layout (4-byte words):
    // flag[16] | indeg_rep[8*NPAD] | bcur[4096] | bucket_base[512] | rowptr[100112]
    // | dinv[NPAD] | buf[8*NBKT*CAP] | dst_sorted[EE] | xbA[N*64] | xbB[N*64]
    // | ybA[N*16] | ybB[N*16]   ~= 87 MB
    int*   flag        = (int*)d_ws;
    int*   indeg_rep   = flag + 16;
    int*   bcur        = indeg_rep + 8 * NPAD;
    int*   bucket_base = bcur + 4096;
    int*   rowptr      = bucket_base + 512;
    float* dinv        = (float*)(rowptr + 100112);
    int*   buf         = (int*)(dinv + NPAD);
    int*   dst_sorted  = buf + (size_t)8 * NBKT * CAP;
    int*   xbA         = dst_sorted + EE;
    int*   xbB         = xbA + (size_t)NN * 64;
    int*   ybA         = xbB + (size_t)NN * 64;
    int*   ybB         = ybA + (size_t)NN * 16;

    const int B = 256;
    const int GW = (NN * 64 + B - 1) / B;   // one wave per row
    const int ZTOT = 8 * NPAD + 4096;

    detect_kernel<<<1, 64, 0, stream>>>((const int*)raw, flag);
    zero_kernel<<<(ZTOT + B - 1) / B, B, 0, stream>>>(indeg_rep, ZTOT);
    passA_kernel<<<(EE + B - 1) / B, B, 0, stream>>>(raw, flag, indeg_rep, bcur, buf);
    bucket_scan_kernel<<<1, 512, 0, stream>>>(bcur, bucket_base, rowptr);
    dinv_kernel<<<(NN + B - 1) / B, B, 0, stream>>>(indeg_rep, dinv);
    passB_kernel<<<NBKT, 256, 0, stream>>>(bcur, buf, bucket_base, rowptr, dst_sorted);

    // hop 1: fp32 in -> bf16 out
    gather_x_t<false, true><<<GW, B, 0, stream>>>(rowptr, dst_sorted, dinv, x0, xbA);
    gather_y_t<false, true><<<GW, B, 0, stream>>>(rowptr, dst_sorted, dinv, y0, ybA);
    // hop 2: bf16 -> bf16
    gather_x_t<true, true><<<GW, B, 0, stream>>>(rowptr, dst_sorted, dinv, xbA, xbB);
    gather_y_t<true, true><<<GW, B, 0, stream>>>(rowptr, dst_sorted, dinv, ybA, ybB);
    // hop 3: bf16 -> bf16
    gather_x_t<true, true><<<GW, B, 0, stream>>>(rowptr, dst_sorted, dinv, xbB, xbA);
    gather_y_t<true, true><<<GW, B, 0, stream>>>(rowptr, dst_sorted, dinv, ybB, ybA);
    // hop 4: bf16 -> fp32 (d_out)
    gather_x_t<true, false><<<GW, B, 0, stream>>>(rowptr, dst_sorted, dinv, xbA, out_x);
    gather_y_t<true, false><<<GW, B, 0, stream>>>(rowptr, dst_sorted, dinv, ybA, out_y);
}

// Round 7
// 692.995 us; speedup vs baseline: 19.4508x; 1.0820x over previous
//
#include <hip/hip_runtime.h>

// APPNP-style propagation: 4 hops of M = 0.9*A_hat + 0.1*I on x[N,128], y[N,32].
// Round 7:
//  (a) passA replica = REAL XCD id via s_getreg(HW_REG_XCC_ID) [m09] -> streams truly
//      XCD-local -> full-line writebacks (R6's blockIdx&7 guess failed: 89 MB WRITE).
//  (b) fused hop kernel: x-loop (4 edges x 16 lanes) + y-loop (16 edges x 4 lanes).
//  (c) pre-scaled bf16 iterates z = dinv*u: inner loop is pure adds, no dinv gather.
//      cast kernel makes hop1 bf16 too; hop4 writes fp32 u to d_out.

#define NN 100000
#define EE 1600000
#define NPAD 100096     // N padded to multiple of 64
#define NBKT 391        // ceil(NN/256); bucket = src >> 8
#define CAP 1024        // per-(bucket,XCD) capacity: Poisson(512) + 22 sigma

#define GETREG_XCC_IMM (((32 - 1) << 11) | (0 << 6) | 20)   // HW_REG_XCC_ID, full width

// ---------- bf16 helpers (RNE) ----------
__device__ __forceinline__ float bflo(unsigned w) { return __uint_as_float(w << 16); }
__device__ __forceinline__ float bfhi(unsigned w) { return __uint_as_float(w & 0xffff0000u); }
__device__ __forceinline__ unsigned packbf(float a, float b) {
    unsigned ua = __float_as_uint(a), ub = __float_as_uint(b);
    unsigned ra = (ua + 0x7fffu + ((ua >> 16) & 1u)) >> 16;
    unsigned rb = (ub + 0x7fffu + ((ub >> 16) & 1u)) >> 16;
    return ra | (rb << 16);
}

// ---------- preprocessing ----------

__global__ void detect_kernel(const int* __restrict__ raw, int* __restrict__ flag) {
    if (threadIdx.x == 0 && blockIdx.x == 0) {
        int is64 = 1;
        for (int k = 1; k < 16; k += 2) {
            if (raw[k] != 0) { is64 = 0; break; }
        }
        *flag = is64;
    }
}

__global__ void zero_kernel(int* __restrict__ bufs, int total) {
    int i = blockIdx.x * blockDim.x + threadIdx.x;
    if (i < total) bufs[i] = 0;
}

// One pass over edges: replicated indeg atomics + bucket append, replica = real XCD id.
__global__ void passA_kernel(const void* __restrict__ raw, const int* __restrict__ flag,
                             int* __restrict__ indeg_rep, int* __restrict__ bcur,
                             int* __restrict__ buf) {
    int e = blockIdx.x * blockDim.x + threadIdx.x;
    int r = __builtin_amdgcn_s_getreg(GETREG_XCC_IMM) & 7;   // wave-uniform XCD id
    if (e < EE) {
        int s, d;
        if (*flag) {
            s = (int)((const long long*)raw)[e];
            d = (int)((const long long*)raw)[EE + e];
        } else {
            s = ((const int*)raw)[e];
            d = ((const int*)raw)[EE + e];
        }
        atomicAdd(&indeg_rep[r * NPAD + d], 1);
        int b = s >> 8;
        int pos = atomicAdd(&bcur[r * 512 + b], 1);
        if (pos < CAP)
            buf[((size_t)(r * NBKT + b)) * CAP + pos] = ((s & 255) << 17) | d;   // d < 2^17
    }
}

// Exclusive prefix over bucket totals -> bucket_base; set rowptr[NN]=EE.
__global__ void bucket_scan_kernel(const int* __restrict__ bcur, int* __restrict__ bucket_base,
                                   int* __restrict__ rowptr) {
    __shared__ int s[512];
    int tid = threadIdx.x;
    int v = 0;
    if (tid < NBKT) {
        #pragma unroll
        for (int r = 0; r < 8; ++r) {
            int c = bcur[r * 512 + tid];
            v += (c < CAP) ? c : CAP;
        }
    }
    s[tid] = v;
    __syncthreads();
    for (int off = 1; off < 512; off <<= 1) {
        int t = (tid >= off) ? s[tid - off] : 0;
        __syncthreads();
        s[tid] += t;
        __syncthreads();
    }
    if (tid < NBKT) bucket_base[tid] = s[tid] - v;
    if (tid == 0) rowptr[NN] = EE;
}

__global__ void dinv_kernel(const int* __restrict__ indeg_rep, float* __restrict__ dinv) {
    int i = blockIdx.x * blockDim.x + threadIdx.x;
    if (i < NN) {
        int ind = 1;
        #pragma unroll
        for (int r = 0; r < 8; ++r) ind += indeg_rep[r * NPAD + i];
        dinv[i] = rsqrtf((float)ind);
    }
}

// Cast fp32 inputs to pre-scaled bf16: zx[i] = dinv[i]*x0[i], zy[i] = dinv[i]*y0[i].
__global__ void cast_kernel(const float4* __restrict__ x0, const float4* __restrict__ y0,
                            const float* __restrict__ dinv, uint4* __restrict__ zx,
                            uint4* __restrict__ zy) {
    int t = blockIdx.x * blockDim.x + threadIdx.x;
    if (t < NN * 16) {
        int node = t >> 4, c = t & 15;
        float di = dinv[node];
        float4 a = x0[(size_t)node * 32 + c * 2];
        float4 b = x0[(size_t)node * 32 + c * 2 + 1];
        uint4 o;
        o.x = packbf(di * a.x, di * a.y); o.y = packbf(di * a.z, di * a.w);
        o.z = packbf(di * b.x, di * b.y); o.w = packbf(di * b.z, di * b.w);
        zx[(size_t)node * 16 + c] = o;
    } else if (t < NN * 20) {
        int u = t - NN * 16;
        int node = u >> 2, c = u & 3;
        float di = dinv[node];
        float4 a = y0[(size_t)node * 8 + c * 2];
        float4 b = y0[(size_t)node * 8 + c * 2 + 1];
        uint4 o;
        o.x = packbf(di * a.x, di * a.y); o.y = packbf(di * a.z, di * a.w);
        o.z = packbf(di * b.x, di * b.y); o.w = packbf(di * b.z, di * b.w);
        zy[(size_t)node * 4 + c] = o;
    }
}

// One WG per bucket: LDS stage -> histogram -> scan -> rowptr + contiguous dst slice.
__global__ __launch_bounds__(256) void passB_kernel(const int* __restrict__ bcur,
                                                    const int* __restrict__ buf,
                                                    const int* __restrict__ bucket_base,
                                                    int* __restrict__ rowptr,
                                                    int* __restrict__ dst_sorted) {
    int b = blockIdx.x;
    int tid = threadIdx.x;
    __shared__ int cnt[8], off[9];
    __shared__ int edges[8 * CAP];      // 32 KB
    __shared__ int hist[256];
    __shared__ int sc[256];
    __shared__ int base_s;

    if (tid < 8) {
        int c = bcur[tid * 512 + b];
        cnt[tid] = (c < CAP) ? c : CAP;
    }
    hist[tid] = 0;
    __syncthreads();
    if (tid == 0) {
        int run = 0;
        #pragma unroll
        for (int r = 0; r < 8; ++r) { off[r] = run; run += cnt[r]; }
        off[8] = run;
        base_s = bucket_base[b];
    }
    __syncthreads();
    #pragma unroll
    for (int r = 0; r < 8; ++r) {
        int c = cnt[r];
        const int* src = buf + ((size_t)(r * NBKT + b)) * CAP;
        for (int i = tid; i < c; i += 256) edges[off[r] + i] = src[i];
    }
    __syncthreads();
    int total = off[8];
    for (int i = tid; i < total; i += 256) atomicAdd(&hist[edges[i] >> 17], 1);
    __syncthreads();
    int hv = hist[tid];
    sc[tid] = hv;
    __syncthreads();
    for (int o = 1; o < 256; o <<= 1) {
        int t = (tid >= o) ? sc[tid - o] : 0;
        __syncthreads();
        sc[tid] += t;
        __syncthreads();
    }
    int excl = sc[tid] - hv;
    int node = (b << 8) + tid;
    if (node < NN) rowptr[node] = base_s + excl;
    hist[tid] = excl;
    __syncthreads();
    for (int i = tid; i < total; i += 256) {
        int p = edges[i];
        int pos = atomicAdd(&hist[p >> 17], 1);
        dst_sorted[base_s + pos] = p & 0x1ffff;
    }
}

// ---------- fused per-hop kernel ----------
// Iterates stored pre-scaled: z = dinv*u (bf16). Per row:
//   u'_row = 0.9*di*sum_e z[d_e] + (0.9*di + 0.1/di)*z_row ; store z' = di*u' (or u' fp32).
template <bool OUTBF>
__global__ __launch_bounds__(256) void hop_kernel(const int* __restrict__ rowptr,
                                                  const int* __restrict__ dst_sorted,
                                                  const float* __restrict__ dinv,
                                                  const uint4* __restrict__ zx,
                                                  const uint4* __restrict__ zy,
                                                  void* __restrict__ nx,
                                                  void* __restrict__ ny) {
    int t = blockIdx.x * blockDim.x + threadIdx.x;
    int row = t >> 6, lane = t & 63;
    if (row >= NN) return;
    int beg = rowptr[row], end = rowptr[row + 1];

    // ---- x: 4 subgroups of 16 lanes, each lane owns 8 columns ----
    int g = lane >> 4, sub = lane & 15;
    float ax[8] = {0.f, 0.f, 0.f, 0.f, 0.f, 0.f, 0.f, 0.f};
    for (int e = beg + g; e < end; e += 4) {
        int d = dst_sorted[e];
        uint4 w = zx[(size_t)d * 16 + sub];
        ax[0] += bflo(w.x); ax[1] += bfhi(w.x);
        ax[2] += bflo(w.y); ax[3] += bfhi(w.y);
        ax[4] += bflo(w.z); ax[5] += bfhi(w.z);
        ax[6] += bflo(w.w); ax[7] += bfhi(w.w);
    }
    #pragma unroll
    for (int m = 16; m <= 32; m <<= 1) {
        #pragma unroll
        for (int i = 0; i < 8; ++i) ax[i] += __shfl_xor(ax[i], m);
    }

    // ---- y: 16 subgroups of 4 lanes, each lane owns 8 columns ----
    int gy = lane >> 2, sy = lane & 3;
    float ay[8] = {0.f, 0.f, 0.f, 0.f, 0.f, 0.f, 0.f, 0.f};
    for (int e = beg + gy; e < end; e += 16) {
        int d = dst_sorted[e];
        uint4 w = zy[(size_t)d * 4 + sy];
        ay[0] += bflo(w.x); ay[1] += bfhi(w.x);
        ay[2] += bflo(w.y); ay[3] += bfhi(w.y);
        ay[4] += bflo(w.z); ay[5] += bfhi(w.z);
        ay[6] += bflo(w.w); ay[7] += bfhi(w.w);
    }
    #pragma unroll
    for (int m = 4; m <= 32; m <<= 1) {
        #pragma unroll
        for (int i = 0; i < 8; ++i) ay[i] += __shfl_xor(ay[i], m);
    }

    float di = dinv[row];
    float sg = 0.9f * di;
    float sl = 0.9f * di + 0.1f / di;   // coefficient on z_row giving the u-space self term

    if (g == 0) {   // lanes 0..15 write x
        uint4 wz = zx[(size_t)row * 16 + sub];
        float c[8] = { bflo(wz.x), bfhi(wz.x), bflo(wz.y), bfhi(wz.y),
                       bflo(wz.z), bfhi(wz.z), bflo(wz.w), bfhi(wz.w) };
        float r[8];
        #pragma unroll
        for (int i = 0; i < 8; ++i) r[i] = sg * ax[i] + sl * c[i];   // u'
        if constexpr (OUTBF) {
            uint4 o;
            o.x = packbf(di * r[0], di * r[1]); o.y = packbf(di * r[2], di * r[3]);
            o.z = packbf(di * r[4], di * r[5]); o.w = packbf(di * r[6], di * r[7]);
            ((uint4*)nx)[(size_t)row * 16 + sub] = o;
        } else {
            float4 a, b;
            a.x = r[0]; a.y = r[1]; a.z = r[2]; a.w = r[3];
            b.x = r[4]; b.y = r[5]; b.z = r[6]; b.w = r[7];
            ((float4*)nx)[(size_t)row * 32 + sub * 2]     = a;
            ((float4*)nx)[(size_t)row * 32 + sub * 2 + 1] = b;
        }
    }
    if (gy == 0) {  // lanes 0..3 write y
        uint4 wz = zy[(size_t)row * 4 + sy];
        float c[8] = { bflo(wz.x), bfhi(wz.x), bflo(wz.y), bfhi(wz.y),
                       bflo(wz.z), bfhi(wz.z), bflo(wz.w), bfhi(wz.w) };
        float r[8];
        #pragma unroll
        for (int i = 0; i < 8; ++i) r[i] = sg * ay[i] + sl * c[i];
        if constexpr (OUTBF) {
            uint4 o;
            o.x = packbf(di * r[0], di * r[1]); o.y = packbf(di * r[2], di * r[3]);
            o.z = packbf(di * r[4], di * r[5]); o.w = packbf(di * r[6], di * r[7]);
            ((uint4*)ny)[(size_t)row * 4 + sy] = o;
        } else {
            float4 a, b;
            a.x = r[0]; a.y = r[1]; a.z = r[2]; a.w = r[3];
            b.x = r[4]; b.y = r[5]; b.z = r[6]; b.w = r[7];
            ((float4*)ny)[(size_t)row * 8 + sy * 2]     = a;
            ((float4*)ny)[(size_t)row * 8 + sy * 2 + 1] = b;
        }
    }
}

extern "C" void kernel_launch(void* const* d_in, const int* in_sizes, int n_in,
                              void* d_out, int out_size, void* d_ws, size_t ws_size,
                              hipStream_t stream) {
    const float* x0  = (const float*)d_in[0];
    const float* y0  = (const float*)d_in[1];
    const void*  raw = d_in[2];

    float* out_x = (float*)d_out;
    float* out_y = out_x + (size_t)NN * 128;

    // ws layout (4-byte words):
    // flag[16] | indeg_rep[8*NPAD] | bcur[4096] | bucket_base[512] | rowptr[100112]
    // | dinv[NPAD] | buf[8*NBKT*CAP] | dst_sorted[EE] | zxA[N*64] | zxB[N*64]
    // | zyA[N*16] | zyB[N*16]   ~= 82 MB
    int*   flag        = (int*)d_ws;
    int*   indeg_rep   = flag + 16;
    int*   bcur        = indeg_rep + 8 * NPAD;
    int*   bucket_base = bcur + 4096;
    int*   rowptr      = bucket_base + 512;
    float* dinv        = (float*)(rowptr + 100112);
    int*   buf         = (int*)(dinv + NPAD);
    int*   dst_sorted  = buf + (size_t)8 * NBKT * CAP;
    uint4* zxA         = (uint4*)(dst_sorted + EE);
    uint4* zxB         = zxA + (size_t)NN * 16;
    uint4* zyA         = (uint4*)(zxB + (size_t)NN * 16);
    uint4* zyB         = zyA + (size_t)NN * 4;

    const int B = 256;
    const int GW = (NN * 64 + B - 1) / B;   // one wave per row
    const int ZTOT = 8 * NPAD + 4096;

    detect_kernel<<<1, 64, 0, stream>>>((const int*)raw, flag);
    zero_kernel<<<(ZTOT + B - 1) / B, B, 0, stream>>>(indeg_rep, ZTOT);
    passA_kernel<<<(EE + B - 1) / B, B, 0, stream>>>(raw, flag, indeg_rep, bcur, buf);
    bucket_scan_kernel<<<1, 512, 0, stream>>>(bcur, bucket_base, rowptr);
    dinv_kernel<<<(NN + B - 1) / B, B, 0, stream>>>(indeg_rep, dinv);
    cast_kernel<<<(NN * 20 + B - 1) / B, B, 0, stream>>>(
        (const float4*)x0, (const float4*)y0, dinv, zxA, zyA);
    passB_kernel<<<NBKT, 256, 0, stream>>>(bcur, buf, bucket_base, rowptr, dst_sorted);

    // hops 1-3: bf16 z -> bf16 z ; hop 4: bf16 z -> fp32 u (d_out)
    hop_kernel<true><<<GW, B, 0, stream>>>(rowptr, dst_sorted, dinv, zxA, zyA, zxB, zyB);
    hop_kernel<true><<<GW, B, 0, stream>>>(rowptr, dst_sorted, dinv, zxB, zyB, zxA, zyA);
    hop_kernel<true><<<GW, B, 0, stream>>>(rowptr, dst_sorted, dinv, zxA, zyA, zxB, zyB);
    hop_kernel<false><<<GW, B, 0, stream>>>(rowptr, dst_sorted, dinv, zxB, zyB, out_x, out_y);
}